// Round 1
// baseline (271.683 us; speedup 1.0000x reference)
//
#include <hip/hip_runtime.h>
#include <math.h>

#define N_NODES 16384
#define DIM 256
#define KNBR 16
#define D2 512

// ---------------------------------------------------------------------------
// K0: Mmat[j,d] = sum_e W_node[j,e] * attenW[e,d]   (M = W_node @ attenW)
// b_node's contribution to logits is constant over k -> softmax-invariant,
// so it is dropped entirely.
// ---------------------------------------------------------------------------
__global__ __launch_bounds__(256) void build_M(const float* __restrict__ W_node,
                                               const float* __restrict__ attenW,
                                               float* __restrict__ Mmat) {
    const int j = blockIdx.x;   // 0..511
    const int d = threadIdx.x;  // 0..255
    float acc = 0.f;
    for (int e = 0; e < DIM; ++e)
        acc = fmaf(W_node[j * DIM + e], attenW[e * DIM + d], acc);
    Mmat[j * DIM + d] = acc;
}

// ---------------------------------------------------------------------------
// Tiled f32 GEMM: C[m,n] = sum_k A[m,k] * B(k,n)  (+ optional resid + bias)
// BT=true : B stored [Ndim][Kdim] (row-major, i.e. C = A @ B^T)
// BT=false: B stored [Kdim][Ndim]
// BM=BN=64, BK=16, 256 threads, 4x4 per thread. All dims assumed divisible.
// ---------------------------------------------------------------------------
template <bool BT, bool RESID>
__global__ __launch_bounds__(256) void gemm64(const float* __restrict__ A,
                                              const float* __restrict__ B,
                                              float* __restrict__ C,
                                              int Kd, int Nd,
                                              const float* __restrict__ resid,
                                              const float* __restrict__ bias,
                                              float bscale) {
    constexpr int BM = 64, BN = 64, BK = 16;
    __shared__ float As[BK][BM + 4];
    __shared__ float Bs[BK][BN + 4];
    const int tid = threadIdx.x;
    const int m0 = blockIdx.x * BM, n0 = blockIdx.y * BN;
    const int ty = tid >> 4, tx = tid & 15;   // 16x16 thread grid
    const int ar = tid >> 2, ac = tid & 3;    // A/B^T tile load: row, float4-col
    const int br = tid >> 4, bc = tid & 15;   // B (normal) tile load

    float acc[4][4] = {};

    for (int k0 = 0; k0 < Kd; k0 += BK) {
        float4 av = *(const float4*)&A[(size_t)(m0 + ar) * Kd + k0 + ac * 4];
        As[ac * 4 + 0][ar] = av.x;
        As[ac * 4 + 1][ar] = av.y;
        As[ac * 4 + 2][ar] = av.z;
        As[ac * 4 + 3][ar] = av.w;
        if (BT) {
            float4 bv = *(const float4*)&B[(size_t)(n0 + ar) * Kd + k0 + ac * 4];
            Bs[ac * 4 + 0][ar] = bv.x;
            Bs[ac * 4 + 1][ar] = bv.y;
            Bs[ac * 4 + 2][ar] = bv.z;
            Bs[ac * 4 + 3][ar] = bv.w;
        } else {
            float4 bv = *(const float4*)&B[(size_t)(k0 + br) * Nd + n0 + bc * 4];
            Bs[br][bc * 4 + 0] = bv.x;
            Bs[br][bc * 4 + 1] = bv.y;
            Bs[br][bc * 4 + 2] = bv.z;
            Bs[br][bc * 4 + 3] = bv.w;
        }
        __syncthreads();
#pragma unroll
        for (int k = 0; k < BK; ++k) {
            float a[4], b[4];
#pragma unroll
            for (int i = 0; i < 4; ++i) a[i] = As[k][ty * 4 + i];
#pragma unroll
            for (int j = 0; j < 4; ++j) b[j] = Bs[k][tx * 4 + j];
#pragma unroll
            for (int i = 0; i < 4; ++i)
#pragma unroll
                for (int j = 0; j < 4; ++j) acc[i][j] = fmaf(a[i], b[j], acc[i][j]);
        }
        __syncthreads();
    }

#pragma unroll
    for (int i = 0; i < 4; ++i) {
#pragma unroll
        for (int j = 0; j < 4; ++j) {
            size_t off = (size_t)(m0 + ty * 4 + i) * Nd + (n0 + tx * 4 + j);
            float v = acc[i][j];
            if (RESID) v = v + resid[off] + bscale * bias[n0 + tx * 4 + j];
            C[off] = v;
        }
    }
}

// ---------------------------------------------------------------------------
// K2: per-node gather + attention + aggregation. One block (256 thr) per node.
// ZR holds Z[n][0:512] on input (z1|z2); overwritten with REP (in_rep+out_rep).
// Safe: block n reads its own row fully before writing it.
// ---------------------------------------------------------------------------
__global__ __launch_bounds__(256) void gather_attn(
    const float* __restrict__ X, const float* __restrict__ Eemb,
    const int* __restrict__ in_idx, const int* __restrict__ in_edge,
    const float* __restrict__ in_mask, const int* __restrict__ out_idx,
    const int* __restrict__ out_edge, const float* __restrict__ out_mask,
    float* __restrict__ ZR) {
    __shared__ __align__(16) float zbuf[D2];
    __shared__ __align__(16) float outx[KNBR][DIM];  // staged out-neighbor rows
    __shared__ float lg[KNBR];
    __shared__ int s_oi[KNBR], s_oe[KNBR], s_ii[KNBR], s_ie[KNBR];
    __shared__ float s_im[KNBR], s_om[KNBR];

    const int n = blockIdx.x;
    const int tid = threadIdx.x;

    // Phase A: load z-row into LDS, stage indices
    zbuf[tid] = ZR[(size_t)n * D2 + tid];
    zbuf[256 + tid] = ZR[(size_t)n * D2 + 256 + tid];
    if (tid < KNBR) {
        s_oi[tid] = out_idx[n * KNBR + tid];
        s_oe[tid] = out_edge[n * KNBR + tid];
        s_ii[tid] = in_idx[n * KNBR + tid];
        s_ie[tid] = in_edge[n * KNBR + tid];
        s_im[tid] = in_mask[n * KNBR + tid];
        s_om[tid] = out_mask[n * KNBR + tid];
    }
    __syncthreads();

    // Phase B: logits. Wave w handles k = 4*kk + w; lane l covers dims 4l..4l+3.
    const int w = tid >> 6, l = tid & 63;
#pragma unroll
    for (int kk = 0; kk < 4; ++kk) {
        const int k = kk * 4 + w;
        const int oi = s_oi[k], oe = s_oe[k];
        float4 xv = *(const float4*)&X[(size_t)oi * DIM + l * 4];
        float4 ev = *(const float4*)&Eemb[(size_t)oe * DIM + l * 4];
        float4 z1 = *(const float4*)&zbuf[l * 4];
        float4 z2 = *(const float4*)&zbuf[256 + l * 4];
        *(float4*)&outx[k][l * 4] = xv;  // stage for aggregation
        float p = xv.x * z1.x + xv.y * z1.y + xv.z * z1.z + xv.w * z1.w +
                  ev.x * z2.x + ev.y * z2.y + ev.z * z2.z + ev.w * z2.w;
#pragma unroll
        for (int off = 32; off > 0; off >>= 1) p += __shfl_down(p, off);
        if (l == 0) lg[k] = p;
    }
    __syncthreads();

    // Phase C: softmax over K=16 (computed redundantly per thread; LDS broadcast)
    float mx = -1e30f;
#pragma unroll
    for (int k = 0; k < KNBR; ++k) mx = fmaxf(mx, lg[k]);
    float al[KNBR], s = 0.f;
#pragma unroll
    for (int k = 0; k < KNBR; ++k) {
        al[k] = __expf(lg[k] - mx);
        s += al[k];
    }
    const float inv = 1.f / s;

    // Phase D: aggregate in_rep + out_rep; thread t owns columns t and 256+t
    float acc1 = 0.f, acc2 = 0.f;
#pragma unroll
    for (int k = 0; k < KNBR; ++k) {
        const float wk = al[k] * inv * s_om[k];
        const float im = s_im[k];
        acc1 += im * X[(size_t)s_ii[k] * DIM + tid] + wk * outx[k][tid];
        acc2 += im * Eemb[(size_t)s_ie[k] * DIM + tid] +
                wk * Eemb[(size_t)s_oe[k] * DIM + tid];
    }
    ZR[(size_t)n * D2 + tid] = acc1;        // same thread read this slot above
    ZR[(size_t)n * D2 + 256 + tid] = acc2;
}

// ---------------------------------------------------------------------------
// K4: MLP readout partial: per block of 64 nodes, t = relu(H@W1 + b1) [64][64],
// reduce over nodes, dot with W2 -> 2 partials per block (deterministic).
// ---------------------------------------------------------------------------
__global__ __launch_bounds__(256) void mlp_reduce(const float* __restrict__ H,
                                                  const float* __restrict__ W1,
                                                  const float* __restrict__ b1,
                                                  const float* __restrict__ W2,
                                                  float* __restrict__ partials) {
    constexpr int BM = 64, BK = 16, NH = 64;
    __shared__ float As[BK][BM + 4];
    __shared__ float Bs[BK][NH + 4];
    __shared__ float red[16][NH];
    const int tid = threadIdx.x;
    const int m0 = blockIdx.x * BM;
    const int ty = tid >> 4, tx = tid & 15;
    const int ar = tid >> 2, ac = tid & 3;
    const int br = tid >> 4, bc = tid & 15;

    float acc[4][4] = {};
    for (int k0 = 0; k0 < DIM; k0 += BK) {
        float4 av = *(const float4*)&H[(size_t)(m0 + ar) * DIM + k0 + ac * 4];
        As[ac * 4 + 0][ar] = av.x;
        As[ac * 4 + 1][ar] = av.y;
        As[ac * 4 + 2][ar] = av.z;
        As[ac * 4 + 3][ar] = av.w;
        float4 bv = *(const float4*)&W1[(size_t)(k0 + br) * NH + bc * 4];
        Bs[br][bc * 4 + 0] = bv.x;
        Bs[br][bc * 4 + 1] = bv.y;
        Bs[br][bc * 4 + 2] = bv.z;
        Bs[br][bc * 4 + 3] = bv.w;
        __syncthreads();
#pragma unroll
        for (int k = 0; k < BK; ++k) {
            float a[4], b[4];
#pragma unroll
            for (int i = 0; i < 4; ++i) a[i] = As[k][ty * 4 + i];
#pragma unroll
            for (int j = 0; j < 4; ++j) b[j] = Bs[k][tx * 4 + j];
#pragma unroll
            for (int i = 0; i < 4; ++i)
#pragma unroll
                for (int j = 0; j < 4; ++j) acc[i][j] = fmaf(a[i], b[j], acc[i][j]);
        }
        __syncthreads();
    }
    // relu + column-sum over the 4 local rows
#pragma unroll
    for (int j = 0; j < 4; ++j) {
        const float bj = b1[tx * 4 + j];
        float sv = 0.f;
#pragma unroll
        for (int i = 0; i < 4; ++i) sv += fmaxf(acc[i][j] + bj, 0.f);
        red[ty][tx * 4 + j] = sv;
    }
    __syncthreads();
    if (tid < 64) {
        float t = 0.f;
        for (int r = 0; r < 16; ++r) t += red[r][tid];
        float h0 = t * W2[tid * 2 + 0];
        float h1 = t * W2[tid * 2 + 1];
#pragma unroll
        for (int off = 32; off > 0; off >>= 1) {
            h0 += __shfl_down(h0, off);
            h1 += __shfl_down(h1, off);
        }
        if (tid == 0) {
            partials[blockIdx.x * 2 + 0] = h0;
            partials[blockIdx.x * 2 + 1] = h1;
        }
    }
}

// ---------------------------------------------------------------------------
// K5: reduce 256 block-partials, add N*b2, softmax over 2 classes
// ---------------------------------------------------------------------------
__global__ void finalize(const float* __restrict__ partials,
                         const float* __restrict__ b2, float* __restrict__ out) {
    const int l = threadIdx.x;  // 64 threads = 1 wave
    float h0 = 0.f, h1 = 0.f;
    for (int i = l; i < 256; i += 64) {
        h0 += partials[2 * i + 0];
        h1 += partials[2 * i + 1];
    }
#pragma unroll
    for (int off = 32; off > 0; off >>= 1) {
        h0 += __shfl_down(h0, off);
        h1 += __shfl_down(h1, off);
    }
    if (l == 0) {
        h0 += (float)N_NODES * b2[0];
        h1 += (float)N_NODES * b2[1];
        const float m = fmaxf(h0, h1);
        const float e0 = __expf(h0 - m), e1 = __expf(h1 - m);
        out[(size_t)N_NODES * DIM + 0] = e0 / (e0 + e1);
        out[(size_t)N_NODES * DIM + 1] = e1 / (e0 + e1);
    }
}

extern "C" void kernel_launch(void* const* d_in, const int* in_sizes, int n_in,
                              void* d_out, int out_size, void* d_ws, size_t ws_size,
                              hipStream_t stream) {
    const float* X = (const float*)d_in[0];
    const int* in_idx = (const int*)d_in[1];
    const int* in_edge = (const int*)d_in[2];
    const float* in_mask = (const float*)d_in[3];
    const int* out_idx = (const int*)d_in[4];
    const int* out_edge = (const int*)d_in[5];
    const float* out_mask = (const float*)d_in[6];
    const float* Eemb = (const float*)d_in[7];
    const float* W_nb = (const float*)d_in[8];
    const float* b_nb = (const float*)d_in[9];
    const float* W_node = (const float*)d_in[10];
    // d_in[11] = b_node: softmax-invariant, unused
    const float* attenW = (const float*)d_in[12];
    const float* W1 = (const float*)d_in[13];
    const float* b1 = (const float*)d_in[14];
    const float* W2 = (const float*)d_in[15];
    const float* b2 = (const float*)d_in[16];
    float* out = (float*)d_out;

    char* ws = (char*)d_ws;
    float* Mmat = (float*)ws;                   // 512*256*4   = 512 KiB
    float* partials = (float*)(ws + 524288);    // 256*2*4     = 2 KiB
    float* ZR = (float*)(ws + 1048576);         // 16384*512*4 = 32 MiB

    // M = W_node @ attenW
    build_M<<<512, 256, 0, stream>>>(W_node, attenW, Mmat);
    // Z[n,j] = sum_d X[n,d] * Mmat[j,d]   (C = X @ M^T)
    gemm64<true, false><<<dim3(256, 8), 256, 0, stream>>>(
        X, Mmat, ZR, DIM, D2, nullptr, nullptr, 0.f);
    // gather + attention + aggregate -> REP (in place over Z)
    gather_attn<<<N_NODES, 256, 0, stream>>>(X, Eemb, in_idx, in_edge, in_mask,
                                             out_idx, out_edge, out_mask, ZR);
    // node_hidden = X + REP @ W_nb + 2*b_nb   (written to d_out)
    gemm64<false, true><<<dim3(256, 4), 256, 0, stream>>>(
        ZR, W_nb, out, D2, DIM, X, b_nb, 2.0f);
    // MLP readout partials, then finalize softmax
    mlp_reduce<<<N_NODES / 64, 256, 0, stream>>>(out, W1, b1, W2, partials);
    finalize<<<1, 64, 0, stream>>>(partials, b2, out);
}

// Round 2
// 181.278 us; speedup vs baseline: 1.4987x; 1.4987x over previous
//
#include <hip/hip_runtime.h>
#include <math.h>

#define N_NODES 16384
#define DIM 256
#define KNBR 16
#define D2 512

typedef __bf16 bf16x8 __attribute__((ext_vector_type(8)));
typedef float f32x4 __attribute__((ext_vector_type(4)));
typedef short short4v __attribute__((ext_vector_type(4)));
typedef short short8v __attribute__((ext_vector_type(8)));
typedef unsigned short u16;
typedef unsigned int u32;

__device__ __forceinline__ u16 f2bf(float x) {
    u32 u = __builtin_bit_cast(u32, x);
    u = u + 0x7FFFu + ((u >> 16) & 1u);   // round-to-nearest-even
    return (u16)(u >> 16);
}
__device__ __forceinline__ float bf2f(u16 h) {
    u32 u = ((u32)h) << 16;
    return __builtin_bit_cast(float, u);
}

// XOR-swizzled LDS index (16B-unit swizzle) for a [rows][64] bf16 tile.
// k in shorts (0..63). Keeps ds_read_b128 fragment reads ~conflict-free.
__device__ __forceinline__ int lds_swz(int row, int k) {
    return (row << 6) + ((((k >> 3) ^ (row & 7)) << 3) | (k & 7));
}

// ---------------------------------------------------------------------------
// pack_tables: Xh = bf16(X); Eh = bf16(Eemb); WnbTh[n][k] = bf16(W_nb[k][n])
// ---------------------------------------------------------------------------
__global__ __launch_bounds__(256) void pack_tables(const float* __restrict__ X,
                                                   const float* __restrict__ Eemb,
                                                   const float* __restrict__ W_nb,
                                                   u16* __restrict__ Xh,
                                                   u16* __restrict__ Eh,
                                                   u16* __restrict__ WnbTh) {
    const int XE = N_NODES * DIM;            // 4194304
    const int EE = 128 * DIM;                // 32768
    const int WE = D2 * DIM;                 // 131072
    const int TOT = XE + EE + WE;
    for (int i = blockIdx.x * 256 + threadIdx.x; i < TOT; i += gridDim.x * 256) {
        if (i < XE) {
            Xh[i] = f2bf(X[i]);
        } else if (i < XE + EE) {
            int j = i - XE;
            Eh[j] = f2bf(Eemb[j]);
        } else {
            int j = i - XE - EE;             // j = n*512 + k
            int n = j >> 9, k = j & 511;
            WnbTh[j] = f2bf(W_nb[k * DIM + n]);
        }
    }
}

// ---------------------------------------------------------------------------
// build_M: M = W_node @ attenW  [512,256], written as hi/lo bf16 split.
// b_node is softmax-invariant (constant over k) -> dropped.
// ---------------------------------------------------------------------------
__global__ __launch_bounds__(256) void build_M(const float* __restrict__ W_node,
                                               const float* __restrict__ attenW,
                                               u16* __restrict__ Mhi,
                                               u16* __restrict__ Mlo) {
    const int j = blockIdx.x;   // 0..511
    const int d = threadIdx.x;  // 0..255
    float acc = 0.f;
    for (int e = 0; e < DIM; ++e)
        acc = fmaf(W_node[j * DIM + e], attenW[e * DIM + d], acc);
    u16 h = f2bf(acc);
    Mhi[j * DIM + d] = h;
    Mlo[j * DIM + d] = f2bf(acc - bf2f(h));
}

// ---------------------------------------------------------------------------
// gemm_z: Z[16384,512] f32 = X @ (Mhi+Mlo)^T with X split hi/lo on the fly.
// 3-product split (hh + hl + lh) => ~f32-accurate z (logits need this).
// BM=128, BN=128, BK=64, 4 waves (2x2), 64x64 per wave, mfma 16x16x32 bf16.
// ---------------------------------------------------------------------------
__global__ __launch_bounds__(256, 2) void gemm_z(const float* __restrict__ X,
                                                 const u16* __restrict__ Mhi,
                                                 const u16* __restrict__ Mlo,
                                                 float* __restrict__ Z) {
    constexpr int BM = 128, BN = 128, BK = 64;
    constexpr int Kd = DIM, Nd = D2;
    __shared__ short Ah[BM * BK], Al[BM * BK], Bh[BN * BK], Bl[BN * BK];
    const int tid = threadIdx.x;
    const int m0 = blockIdx.x * BM, n0 = blockIdx.y * BN;
    const int w = tid >> 6, lane = tid & 63;
    const int wr = (w >> 1) * 64, wc = (w & 1) * 64;
    const int lrow = lane & 15, lkg = lane >> 4;

    f32x4 acc[4][4] = {};

    for (int k0 = 0; k0 < Kd; k0 += BK) {
        // stage A: 128x64 f32 -> hi/lo bf16 (split on the fly)
#pragma unroll
        for (int i = 0; i < 8; ++i) {
            int idx = i * 256 + tid;                 // 0..2047
            int r = idx >> 4, c4 = (idx & 15) << 2;  // k-offset in shorts
            float4 v = *(const float4*)&X[(size_t)(m0 + r) * Kd + k0 + c4];
            u16 h0 = f2bf(v.x), h1 = f2bf(v.y), h2 = f2bf(v.z), h3 = f2bf(v.w);
            short4v hv = {(short)h0, (short)h1, (short)h2, (short)h3};
            short4v lv = {(short)f2bf(v.x - bf2f(h0)), (short)f2bf(v.y - bf2f(h1)),
                          (short)f2bf(v.z - bf2f(h2)), (short)f2bf(v.w - bf2f(h3))};
            int li = lds_swz(r, c4);
            *(short4v*)&Ah[li] = hv;
            *(short4v*)&Al[li] = lv;
        }
        // stage B: 128x64 bf16 hi and lo
#pragma unroll
        for (int i = 0; i < 4; ++i) {
            int idx = i * 256 + tid;                 // 0..1023
            int r = idx >> 3, c8 = (idx & 7) << 3;
            int li = lds_swz(r, c8);
            *(short8v*)&Bh[li] = *(const short8v*)&Mhi[(size_t)(n0 + r) * Kd + k0 + c8];
            *(short8v*)&Bl[li] = *(const short8v*)&Mlo[(size_t)(n0 + r) * Kd + k0 + c8];
        }
        __syncthreads();
#pragma unroll
        for (int kk = 0; kk < 2; ++kk) {
            const int kof = kk * 32 + lkg * 8;
            bf16x8 ah[4], al[4], bh[4], bl[4];
#pragma unroll
            for (int i = 0; i < 4; ++i) {
                int li = lds_swz(wr + i * 16 + lrow, kof);
                ah[i] = *(const bf16x8*)&Ah[li];
                al[i] = *(const bf16x8*)&Al[li];
            }
#pragma unroll
            for (int j = 0; j < 4; ++j) {
                int li = lds_swz(wc + j * 16 + lrow, kof);
                bh[j] = *(const bf16x8*)&Bh[li];
                bl[j] = *(const bf16x8*)&Bl[li];
            }
#pragma unroll
            for (int i = 0; i < 4; ++i)
#pragma unroll
                for (int j = 0; j < 4; ++j) {
                    acc[i][j] = __builtin_amdgcn_mfma_f32_16x16x32_bf16(ah[i], bh[j], acc[i][j], 0, 0, 0);
                    acc[i][j] = __builtin_amdgcn_mfma_f32_16x16x32_bf16(ah[i], bl[j], acc[i][j], 0, 0, 0);
                    acc[i][j] = __builtin_amdgcn_mfma_f32_16x16x32_bf16(al[i], bh[j], acc[i][j], 0, 0, 0);
                }
        }
        __syncthreads();
    }
    // epilogue: C/D layout col=lane&15, row=(lane>>4)*4+reg  [verified m89]
#pragma unroll
    for (int i = 0; i < 4; ++i)
#pragma unroll
        for (int j = 0; j < 4; ++j)
#pragma unroll
            for (int r = 0; r < 4; ++r) {
                int row = m0 + wr + i * 16 + lkg * 4 + r;
                int col = n0 + wc + j * 16 + lrow;
                Z[(size_t)row * Nd + col] = acc[i][j][r];
            }
}

// ---------------------------------------------------------------------------
// gather_attn: per-node gather + attention + aggregation.
// Out-side X gathered in f32 (feeds logits: std~16, needs precision), staged
// to LDS as bf16 for aggregation. In-side gathered bf16 (precision-benign).
// REP written bf16 IN PLACE into Z row n (first 1024B of the 2048B row).
// ---------------------------------------------------------------------------
__global__ __launch_bounds__(256) void gather_attn(
    const float* __restrict__ X, const u16* __restrict__ Xh,
    const u16* __restrict__ Eh,
    const int* __restrict__ in_idx, const int* __restrict__ in_edge,
    const float* __restrict__ in_mask, const int* __restrict__ out_idx,
    const int* __restrict__ out_edge, const float* __restrict__ out_mask,
    float* __restrict__ Z) {
    __shared__ __align__(16) float zbuf[D2];
    __shared__ __align__(16) u16 outxh[KNBR][DIM];
    __shared__ float lg[KNBR];
    __shared__ int s_oi[KNBR], s_oe[KNBR], s_ii[KNBR], s_ie[KNBR];
    __shared__ float s_im[KNBR], s_om[KNBR];

    const int n = blockIdx.x;
    const int tid = threadIdx.x;

    // Phase A: z-row -> LDS, stage indices
    zbuf[tid] = Z[(size_t)n * D2 + tid];
    zbuf[256 + tid] = Z[(size_t)n * D2 + 256 + tid];
    if (tid < KNBR) {
        s_oi[tid] = out_idx[n * KNBR + tid];
        s_oe[tid] = out_edge[n * KNBR + tid];
        s_ii[tid] = in_idx[n * KNBR + tid];
        s_ie[tid] = in_edge[n * KNBR + tid];
        s_im[tid] = in_mask[n * KNBR + tid];
        s_om[tid] = out_mask[n * KNBR + tid];
    }
    __syncthreads();

    // Phase B: logits (f32). Wave w handles k = 4*kk + w; lane l dims 4l..4l+3.
    const int w = tid >> 6, l = tid & 63;
#pragma unroll
    for (int kk = 0; kk < 4; ++kk) {
        const int k = kk * 4 + w;
        const int oi = s_oi[k], oe = s_oe[k];
        float4 xv = *(const float4*)&X[(size_t)oi * DIM + l * 4];
        float4 z1 = *(const float4*)&zbuf[l * 4];
        float4 z2 = *(const float4*)&zbuf[256 + l * 4];
        float e0 = bf2f(Eh[(size_t)oe * DIM + l * 4 + 0]);
        float e1 = bf2f(Eh[(size_t)oe * DIM + l * 4 + 1]);
        float e2 = bf2f(Eh[(size_t)oe * DIM + l * 4 + 2]);
        float e3 = bf2f(Eh[(size_t)oe * DIM + l * 4 + 3]);
        short4v sv = {(short)f2bf(xv.x), (short)f2bf(xv.y),
                      (short)f2bf(xv.z), (short)f2bf(xv.w)};
        *(short4v*)&outxh[k][l * 4] = sv;   // stage bf16 for aggregation
        float p = xv.x * z1.x + xv.y * z1.y + xv.z * z1.z + xv.w * z1.w +
                  e0 * z2.x + e1 * z2.y + e2 * z2.z + e3 * z2.w;
#pragma unroll
        for (int off = 32; off > 0; off >>= 1) p += __shfl_down(p, off);
        if (l == 0) lg[k] = p;
    }
    __syncthreads();

    // Phase C: softmax over K=16 (redundant per thread, LDS broadcast)
    float mx = -1e30f;
#pragma unroll
    for (int k = 0; k < KNBR; ++k) mx = fmaxf(mx, lg[k]);
    float al[KNBR], s = 0.f;
#pragma unroll
    for (int k = 0; k < KNBR; ++k) {
        al[k] = __expf(lg[k] - mx);
        s += al[k];
    }
    const float inv = 1.f / s;

    // Phase D: aggregate; thread t owns cols t (node part) and 256+t (edge part)
    float acc1 = 0.f, acc2 = 0.f;
#pragma unroll
    for (int k = 0; k < KNBR; ++k) {
        const float wk = al[k] * inv * s_om[k];
        const float im = s_im[k];
        acc1 += im * bf2f(Xh[(size_t)s_ii[k] * DIM + tid]) + wk * bf2f(outxh[k][tid]);
        acc2 += im * bf2f(Eh[(size_t)s_ie[k] * DIM + tid]) +
                wk * bf2f(Eh[(size_t)s_oe[k] * DIM + tid]);
    }
    u16* REPh = (u16*)Z;   // row n: first 1024 ushorts of the 2048B f32 row
    REPh[(size_t)n * 1024 + tid] = f2bf(acc1);
    REPh[(size_t)n * 1024 + 256 + tid] = f2bf(acc2);
}

// ---------------------------------------------------------------------------
// gemm_h: out[16384,256] = REPh @ WnbTh^T + X + 2*b_nb   (bf16 MFMA, f32 out)
// A = REPh with row pitch 1024 shorts (aliased in Z). BM=128,BN=128,BK=64.
// ---------------------------------------------------------------------------
__global__ __launch_bounds__(256, 3) void gemm_h(const u16* __restrict__ A,
                                                 const u16* __restrict__ B,
                                                 const float* __restrict__ X,
                                                 const float* __restrict__ b_nb,
                                                 float* __restrict__ out) {
    constexpr int BM = 128, BN = 128, BK = 64;
    constexpr int Kd = D2, Nd = DIM, LDA = 1024;
    __shared__ short Ah[BM * BK], Bh[BN * BK];
    const int tid = threadIdx.x;
    const int m0 = blockIdx.x * BM, n0 = blockIdx.y * BN;
    const int w = tid >> 6, lane = tid & 63;
    const int wr = (w >> 1) * 64, wc = (w & 1) * 64;
    const int lrow = lane & 15, lkg = lane >> 4;

    f32x4 acc[4][4] = {};

    for (int k0 = 0; k0 < Kd; k0 += BK) {
#pragma unroll
        for (int i = 0; i < 4; ++i) {
            int idx = i * 256 + tid;
            int r = idx >> 3, c8 = (idx & 7) << 3;
            int li = lds_swz(r, c8);
            *(short8v*)&Ah[li] = *(const short8v*)&A[(size_t)(m0 + r) * LDA + k0 + c8];
            *(short8v*)&Bh[li] = *(const short8v*)&B[(size_t)(n0 + r) * Kd + k0 + c8];
        }
        __syncthreads();
#pragma unroll
        for (int kk = 0; kk < 2; ++kk) {
            const int kof = kk * 32 + lkg * 8;
            bf16x8 a[4], b[4];
#pragma unroll
            for (int i = 0; i < 4; ++i) a[i] = *(const bf16x8*)&Ah[lds_swz(wr + i * 16 + lrow, kof)];
#pragma unroll
            for (int j = 0; j < 4; ++j) b[j] = *(const bf16x8*)&Bh[lds_swz(wc + j * 16 + lrow, kof)];
#pragma unroll
            for (int i = 0; i < 4; ++i)
#pragma unroll
                for (int j = 0; j < 4; ++j)
                    acc[i][j] = __builtin_amdgcn_mfma_f32_16x16x32_bf16(a[i], b[j], acc[i][j], 0, 0, 0);
        }
        __syncthreads();
    }
#pragma unroll
    for (int i = 0; i < 4; ++i)
#pragma unroll
        for (int j = 0; j < 4; ++j)
#pragma unroll
            for (int r = 0; r < 4; ++r) {
                int row = m0 + wr + i * 16 + lkg * 4 + r;
                int col = n0 + wc + j * 16 + lrow;
                size_t off = (size_t)row * Nd + col;
                out[off] = acc[i][j][r] + X[off] + 2.0f * b_nb[col];
            }
}

// ---------------------------------------------------------------------------
// mlp_reduce + finalize: unchanged from round 1 (f32, deterministic 2-stage)
// ---------------------------------------------------------------------------
__global__ __launch_bounds__(256) void mlp_reduce(const float* __restrict__ H,
                                                  const float* __restrict__ W1,
                                                  const float* __restrict__ b1,
                                                  const float* __restrict__ W2,
                                                  float* __restrict__ partials) {
    constexpr int BM = 64, BK = 16, NH = 64;
    __shared__ float As[BK][BM + 4];
    __shared__ float Bs[BK][NH + 4];
    __shared__ float red[16][NH];
    const int tid = threadIdx.x;
    const int m0 = blockIdx.x * BM;
    const int ty = tid >> 4, tx = tid & 15;
    const int ar = tid >> 2, ac = tid & 3;
    const int br = tid >> 4, bc = tid & 15;

    float acc[4][4] = {};
    for (int k0 = 0; k0 < DIM; k0 += BK) {
        float4 av = *(const float4*)&H[(size_t)(m0 + ar) * DIM + k0 + ac * 4];
        As[ac * 4 + 0][ar] = av.x;
        As[ac * 4 + 1][ar] = av.y;
        As[ac * 4 + 2][ar] = av.z;
        As[ac * 4 + 3][ar] = av.w;
        float4 bv = *(const float4*)&W1[(size_t)(k0 + br) * NH + bc * 4];
        Bs[br][bc * 4 + 0] = bv.x;
        Bs[br][bc * 4 + 1] = bv.y;
        Bs[br][bc * 4 + 2] = bv.z;
        Bs[br][bc * 4 + 3] = bv.w;
        __syncthreads();
#pragma unroll
        for (int k = 0; k < BK; ++k) {
            float a[4], b[4];
#pragma unroll
            for (int i = 0; i < 4; ++i) a[i] = As[k][ty * 4 + i];
#pragma unroll
            for (int j = 0; j < 4; ++j) b[j] = Bs[k][tx * 4 + j];
#pragma unroll
            for (int i = 0; i < 4; ++i)
#pragma unroll
                for (int j = 0; j < 4; ++j) acc[i][j] = fmaf(a[i], b[j], acc[i][j]);
        }
        __syncthreads();
    }
#pragma unroll
    for (int j = 0; j < 4; ++j) {
        const float bj = b1[tx * 4 + j];
        float sv = 0.f;
#pragma unroll
        for (int i = 0; i < 4; ++i) sv += fmaxf(acc[i][j] + bj, 0.f);
        red[ty][tx * 4 + j] = sv;
    }
    __syncthreads();
    if (tid < 64) {
        float t = 0.f;
        for (int r = 0; r < 16; ++r) t += red[r][tid];
        float h0 = t * W2[tid * 2 + 0];
        float h1 = t * W2[tid * 2 + 1];
#pragma unroll
        for (int off = 32; off > 0; off >>= 1) {
            h0 += __shfl_down(h0, off);
            h1 += __shfl_down(h1, off);
        }
        if (tid == 0) {
            partials[blockIdx.x * 2 + 0] = h0;
            partials[blockIdx.x * 2 + 1] = h1;
        }
    }
}

__global__ void finalize(const float* __restrict__ partials,
                         const float* __restrict__ b2, float* __restrict__ out) {
    const int l = threadIdx.x;
    float h0 = 0.f, h1 = 0.f;
    for (int i = l; i < 256; i += 64) {
        h0 += partials[2 * i + 0];
        h1 += partials[2 * i + 1];
    }
#pragma unroll
    for (int off = 32; off > 0; off >>= 1) {
        h0 += __shfl_down(h0, off);
        h1 += __shfl_down(h1, off);
    }
    if (l == 0) {
        h0 += (float)N_NODES * b2[0];
        h1 += (float)N_NODES * b2[1];
        const float m = fmaxf(h0, h1);
        const float e0 = __expf(h0 - m), e1 = __expf(h1 - m);
        out[(size_t)N_NODES * DIM + 0] = e0 / (e0 + e1);
        out[(size_t)N_NODES * DIM + 1] = e1 / (e0 + e1);
    }
}

extern "C" void kernel_launch(void* const* d_in, const int* in_sizes, int n_in,
                              void* d_out, int out_size, void* d_ws, size_t ws_size,
                              hipStream_t stream) {
    const float* X = (const float*)d_in[0];
    const int* in_idx = (const int*)d_in[1];
    const int* in_edge = (const int*)d_in[2];
    const float* in_mask = (const float*)d_in[3];
    const int* out_idx = (const int*)d_in[4];
    const int* out_edge = (const int*)d_in[5];
    const float* out_mask = (const float*)d_in[6];
    const float* Eemb = (const float*)d_in[7];
    const float* W_nb = (const float*)d_in[8];
    const float* b_nb = (const float*)d_in[9];
    const float* W_node = (const float*)d_in[10];
    // d_in[11] = b_node: zeros AND softmax-invariant -> unused
    const float* attenW = (const float*)d_in[12];
    const float* W1 = (const float*)d_in[13];
    const float* b1 = (const float*)d_in[14];
    const float* W2 = (const float*)d_in[15];
    const float* b2 = (const float*)d_in[16];
    float* out = (float*)d_out;

    char* ws = (char*)d_ws;
    float* Z = (float*)ws;                         // 32 MiB (REPh aliases rows)
    u16* Xh = (u16*)(ws + 33554432);               // 8 MiB
    u16* Mhi = (u16*)(ws + 41943040);              // 256 KiB
    u16* Mlo = (u16*)(ws + 42205184);              // 256 KiB
    u16* WnbTh = (u16*)(ws + 42467328);            // 256 KiB
    u16* Eh = (u16*)(ws + 42729472);               // 64 KiB
    float* partials = (float*)(ws + 42795008);     // 2 KiB

    pack_tables<<<2048, 256, 0, stream>>>(X, Eemb, W_nb, Xh, Eh, WnbTh);
    build_M<<<512, 256, 0, stream>>>(W_node, attenW, Mhi, Mlo);
    gemm_z<<<dim3(128, 4), 256, 0, stream>>>(X, Mhi, Mlo, Z);
    gather_attn<<<N_NODES, 256, 0, stream>>>(X, Xh, Eh, in_idx, in_edge, in_mask,
                                             out_idx, out_edge, out_mask, Z);
    gemm_h<<<dim3(128, 2), 256, 0, stream>>>((const u16*)Z, WnbTh, X, b_nb, out);
    mlp_reduce<<<N_NODES / 64, 256, 0, stream>>>(out, W1, b1, W2, partials);
    finalize<<<1, 64, 0, stream>>>(partials, b2, out);
}

// Round 3
// 132.876 us; speedup vs baseline: 2.0446x; 1.3643x over previous
//
#include <hip/hip_runtime.h>
#include <math.h>

#define N_NODES 16384
#define DIM 256
#define KNBR 16
#define D2 512

typedef __bf16 bf16x8 __attribute__((ext_vector_type(8)));
typedef float f32x4 __attribute__((ext_vector_type(4)));
typedef short short4v __attribute__((ext_vector_type(4)));
typedef short short8v __attribute__((ext_vector_type(8)));
typedef unsigned int u32;
typedef u32 u32x4 __attribute__((ext_vector_type(4)));
typedef unsigned short u16;

__device__ __forceinline__ u16 f2bf(float x) {
    u32 u = __builtin_bit_cast(u32, x);
    u = u + 0x7FFFu + ((u >> 16) & 1u);   // round-to-nearest-even
    return (u16)(u >> 16);
}
__device__ __forceinline__ float bf2f(u16 h) {
    u32 u = ((u32)h) << 16;
    return __builtin_bit_cast(float, u);
}

// XOR-swizzled LDS index (16B-unit swizzle) for a [rows][64] bf16 tile.
__device__ __forceinline__ int lds_swz(int row, int k) {
    return (row << 6) + ((((k >> 3) ^ (row & 7)) << 3) | (k & 7));
}

// ---------------------------------------------------------------------------
// pack_tables: XE[0:16384) = bf16(X) rows; XE[16384:16512) = bf16(Eemb) rows
// (one contiguous gather table); WnbTh[n][k] = bf16(W_nb[k][n]).
// ---------------------------------------------------------------------------
__global__ __launch_bounds__(256) void pack_tables(const float* __restrict__ X,
                                                   const float* __restrict__ Eemb,
                                                   const float* __restrict__ W_nb,
                                                   u16* __restrict__ XE,
                                                   u16* __restrict__ WnbTh) {
    const int XN = N_NODES * DIM;            // 4194304
    const int EE = 128 * DIM;                // 32768
    const int WE = D2 * DIM;                 // 131072
    const int TOT = XN + EE + WE;
    for (int i = blockIdx.x * 256 + threadIdx.x; i < TOT; i += gridDim.x * 256) {
        if (i < XN) {
            XE[i] = f2bf(X[i]);
        } else if (i < XN + EE) {
            XE[i] = f2bf(Eemb[i - XN]);      // Eemb rows appended
        } else {
            int j = i - XN - EE;             // j = n*512 + k
            int n = j >> 9, k = j & 511;
            WnbTh[j] = f2bf(W_nb[k * DIM + n]);
        }
    }
}

// ---------------------------------------------------------------------------
// build_M: M = W_node @ attenW [512,256] as hi/lo bf16 split.
// b_node is softmax-invariant (constant over k) -> dropped.
// ---------------------------------------------------------------------------
__global__ __launch_bounds__(256) void build_M(const float* __restrict__ W_node,
                                               const float* __restrict__ attenW,
                                               u16* __restrict__ Mhi,
                                               u16* __restrict__ Mlo) {
    const int j = blockIdx.x;
    const int d = threadIdx.x;
    float acc = 0.f;
    for (int e = 0; e < DIM; ++e)
        acc = fmaf(W_node[j * DIM + e], attenW[e * DIM + d], acc);
    u16 h = f2bf(acc);
    Mhi[j * DIM + d] = h;
    Mlo[j * DIM + d] = f2bf(acc - bf2f(h));
}

// ---------------------------------------------------------------------------
// gemm_z: Zh[16384,512] bf16 = Xh @ (Mhi+Mlo)^T.  2 MFMA products (hh + hl).
// BM=128, BN=128, BK=64, 4 waves (2x2), mfma 16x16x32 bf16.
// ---------------------------------------------------------------------------
__global__ __launch_bounds__(256, 2) void gemm_z(const u16* __restrict__ Xh,
                                                 const u16* __restrict__ Mhi,
                                                 const u16* __restrict__ Mlo,
                                                 u16* __restrict__ Zh) {
    constexpr int BM = 128, BN = 128, BK = 64;
    constexpr int Kd = DIM, Nd = D2;
    __shared__ short Ah[BM * BK], Bh[BN * BK], Bl[BN * BK];
    const int tid = threadIdx.x;
    const int m0 = blockIdx.x * BM, n0 = blockIdx.y * BN;
    const int w = tid >> 6, lane = tid & 63;
    const int wr = (w >> 1) * 64, wc = (w & 1) * 64;
    const int lrow = lane & 15, lkg = lane >> 4;

    f32x4 acc[4][4] = {};

    for (int k0 = 0; k0 < Kd; k0 += BK) {
#pragma unroll
        for (int i = 0; i < 4; ++i) {
            int idx = i * 256 + tid;                 // 1024 short8 slots
            int r = idx >> 3, c8 = (idx & 7) << 3;
            int li = lds_swz(r, c8);
            *(short8v*)&Ah[li] = *(const short8v*)&Xh[(size_t)(m0 + r) * Kd + k0 + c8];
            *(short8v*)&Bh[li] = *(const short8v*)&Mhi[(size_t)(n0 + r) * Kd + k0 + c8];
            *(short8v*)&Bl[li] = *(const short8v*)&Mlo[(size_t)(n0 + r) * Kd + k0 + c8];
        }
        __syncthreads();
#pragma unroll
        for (int kk = 0; kk < 2; ++kk) {
            const int kof = kk * 32 + lkg * 8;
            bf16x8 a[4], bh[4], bl[4];
#pragma unroll
            for (int i = 0; i < 4; ++i) a[i] = *(const bf16x8*)&Ah[lds_swz(wr + i * 16 + lrow, kof)];
#pragma unroll
            for (int j = 0; j < 4; ++j) {
                bh[j] = *(const bf16x8*)&Bh[lds_swz(wc + j * 16 + lrow, kof)];
                bl[j] = *(const bf16x8*)&Bl[lds_swz(wc + j * 16 + lrow, kof)];
            }
#pragma unroll
            for (int i = 0; i < 4; ++i)
#pragma unroll
                for (int j = 0; j < 4; ++j) {
                    acc[i][j] = __builtin_amdgcn_mfma_f32_16x16x32_bf16(a[i], bh[j], acc[i][j], 0, 0, 0);
                    acc[i][j] = __builtin_amdgcn_mfma_f32_16x16x32_bf16(a[i], bl[j], acc[i][j], 0, 0, 0);
                }
        }
        __syncthreads();
    }
#pragma unroll
    for (int i = 0; i < 4; ++i)
#pragma unroll
        for (int j = 0; j < 4; ++j)
#pragma unroll
            for (int r = 0; r < 4; ++r) {
                int row = m0 + wr + i * 16 + lkg * 4 + r;
                int col = n0 + wc + j * 16 + lrow;
                Zh[(size_t)row * Nd + col] = f2bf(acc[i][j][r]);
            }
}

// ---------------------------------------------------------------------------
// gather_attn: ONE WAVE PER NODE (4 nodes / 256-thread block).
// Lane l owns 8 dims of the 512-dim concat(node,edge) space.
// Out-rows gathered once as short8, stashed in 64 VGPRs across phases.
// Logit reduce: rotated LDS transpose + 2 shfl_xor. Softmax once per wave.
// REP (bf16) overwrites Zh row n in place (same lane reads z then writes REP).
// ---------------------------------------------------------------------------
#define NPB 4
__global__ __launch_bounds__(256) void gather_attn(
    const u16* __restrict__ XE,   // [16512][256] bf16 (X rows, then Eemb rows)
    const int* __restrict__ in_idx, const int* __restrict__ in_edge,
    const float* __restrict__ in_mask, const int* __restrict__ out_idx,
    const int* __restrict__ out_edge, const float* __restrict__ out_mask,
    u16* __restrict__ Zh) {
    __shared__ float s_red[NPB][64 * 16];
    __shared__ int s_oi[NPB][KNBR], s_oe[NPB][KNBR];
    __shared__ int s_ii[NPB][KNBR], s_ie[NPB][KNBR];
    __shared__ float s_im[NPB][KNBR], s_om[NPB][KNBR], s_wt[NPB][KNBR];

    const int tid = threadIdx.x;
    const int w = tid >> 6, lane = tid & 63;
    const int n = blockIdx.x * NPB + w;

    if (lane < KNBR) {
        int g = n * KNBR + lane;
        s_oi[w][lane] = out_idx[g];
        s_oe[w][lane] = N_NODES + out_edge[g];
        s_ii[w][lane] = in_idx[g];
        s_ie[w][lane] = N_NODES + in_edge[g];
        s_im[w][lane] = in_mask[g];
        s_om[w][lane] = out_mask[g];
    }
    // z slice: lane l holds concat dims [8l, 8l+8) in registers
    float zr[8];
    {
        short8v zv = *(const short8v*)&Zh[(size_t)n * D2 + lane * 8];
#pragma unroll
        for (int c = 0; c < 8; ++c) zr[c] = bf2f((u16)zv[c]);
    }
    __syncthreads();

    const int d8 = (lane & 31) * 8;   // dim offset within the 256-half

    // Phase B: gather out-rows (stash) + logit partials
    u32x4 stash[KNBR];
    float p[KNBR];
#pragma unroll
    for (int k = 0; k < KNBR; ++k) {
        int r = (lane < 32) ? s_oi[w][k] : s_oe[w][k];
        short8v v = *(const short8v*)&XE[(size_t)r * DIM + d8];
        stash[k] = __builtin_bit_cast(u32x4, v);
        float q = 0.f;
#pragma unroll
        for (int c = 0; c < 8; ++c) q = fmaf(bf2f((u16)v[c]), zr[c], q);
        p[k] = q;
    }

    // Reduce: rotated LDS transpose (64 lanes x 16 k) then quarter-combine
    float* red = s_red[w];
#pragma unroll
    for (int k0 = 0; k0 < KNBR; k0 += 4) {
        f32x4 q = {p[k0], p[k0 + 1], p[k0 + 2], p[k0 + 3]};
        int col = (k0 + 4 * lane) & 15;
        *(f32x4*)&red[lane * 16 + col] = q;
    }
    __syncthreads();
    float t = 0.f;
#pragma unroll
    for (int i = 0; i < 16; ++i) {
        int row = (lane >> 4) * 16 + i;
        int col = ((lane & 15) + 4 * row) & 15;
        t += red[row * 16 + col];
    }
    t += __shfl_xor(t, 16);
    t += __shfl_xor(t, 32);
    // t = logit[lane & 15] on every lane

    // Softmax over 16 k's (butterfly within 16-lane groups)
    float m = t;
#pragma unroll
    for (int d = 1; d < 16; d <<= 1) m = fmaxf(m, __shfl_xor(m, d));
    float e = __expf(t - m);
    float s = e;
#pragma unroll
    for (int d = 1; d < 16; d <<= 1) s += __shfl_xor(s, d);
    float wt = e / s * s_om[w][lane & 15];
    if (lane < KNBR) s_wt[w][lane] = wt;
    __syncthreads();

    // Phase D: in-side gather + stashed out-side, weighted accumulate
    float acc[8] = {};
#pragma unroll
    for (int k = 0; k < KNBR; ++k) {
        int r = (lane < 32) ? s_ii[w][k] : s_ie[w][k];
        short8v vin = *(const short8v*)&XE[(size_t)r * DIM + d8];
        short8v vout = __builtin_bit_cast(short8v, stash[k]);
        float imk = s_im[w][k], wtk = s_wt[w][k];
#pragma unroll
        for (int c = 0; c < 8; ++c) {
            acc[c] = fmaf(imk, bf2f((u16)vin[c]), acc[c]);
            acc[c] = fmaf(wtk, bf2f((u16)vout[c]), acc[c]);
        }
    }
    short8v ov;
#pragma unroll
    for (int c = 0; c < 8; ++c) ov[c] = (short)f2bf(acc[c]);
    *(short8v*)&Zh[(size_t)n * D2 + lane * 8] = ov;   // REP overlays z row
}

// ---------------------------------------------------------------------------
// gemm_h: out[16384,256] = REP @ WnbTh^T + X + 2*b_nb  (bf16 MFMA, f32 out)
// A = REP rows in Zh, pitch 512 shorts. BM=128, BN=128, BK=64.
// ---------------------------------------------------------------------------
__global__ __launch_bounds__(256, 3) void gemm_h(const u16* __restrict__ A,
                                                 const u16* __restrict__ B,
                                                 const float* __restrict__ X,
                                                 const float* __restrict__ b_nb,
                                                 float* __restrict__ out) {
    constexpr int BM = 128, BN = 128, BK = 64;
    constexpr int Kd = D2, Nd = DIM;
    __shared__ short Ah[BM * BK], Bh[BN * BK];
    const int tid = threadIdx.x;
    const int m0 = blockIdx.x * BM, n0 = blockIdx.y * BN;
    const int w = tid >> 6, lane = tid & 63;
    const int wr = (w >> 1) * 64, wc = (w & 1) * 64;
    const int lrow = lane & 15, lkg = lane >> 4;

    f32x4 acc[4][4] = {};

    for (int k0 = 0; k0 < Kd; k0 += BK) {
#pragma unroll
        for (int i = 0; i < 4; ++i) {
            int idx = i * 256 + tid;
            int r = idx >> 3, c8 = (idx & 7) << 3;
            int li = lds_swz(r, c8);
            *(short8v*)&Ah[li] = *(const short8v*)&A[(size_t)(m0 + r) * Kd + k0 + c8];
            *(short8v*)&Bh[li] = *(const short8v*)&B[(size_t)(n0 + r) * Kd + k0 + c8];
        }
        __syncthreads();
#pragma unroll
        for (int kk = 0; kk < 2; ++kk) {
            const int kof = kk * 32 + lkg * 8;
            bf16x8 a[4], b[4];
#pragma unroll
            for (int i = 0; i < 4; ++i) a[i] = *(const bf16x8*)&Ah[lds_swz(wr + i * 16 + lrow, kof)];
#pragma unroll
            for (int j = 0; j < 4; ++j) b[j] = *(const bf16x8*)&Bh[lds_swz(wc + j * 16 + lrow, kof)];
#pragma unroll
            for (int i = 0; i < 4; ++i)
#pragma unroll
                for (int j = 0; j < 4; ++j)
                    acc[i][j] = __builtin_amdgcn_mfma_f32_16x16x32_bf16(a[i], b[j], acc[i][j], 0, 0, 0);
        }
        __syncthreads();
    }
#pragma unroll
    for (int i = 0; i < 4; ++i)
#pragma unroll
        for (int j = 0; j < 4; ++j)
#pragma unroll
            for (int r = 0; r < 4; ++r) {
                int row = m0 + wr + i * 16 + lkg * 4 + r;
                int col = n0 + wc + j * 16 + lrow;
                size_t off = (size_t)row * Nd + col;
                out[off] = acc[i][j][r] + X[off] + 2.0f * b_nb[col];
            }
}

// ---------------------------------------------------------------------------
// mlp_reduce + finalize (f32, deterministic 2-stage)
// ---------------------------------------------------------------------------
__global__ __launch_bounds__(256) void mlp_reduce(const float* __restrict__ H,
                                                  const float* __restrict__ W1,
                                                  const float* __restrict__ b1,
                                                  const float* __restrict__ W2,
                                                  float* __restrict__ partials) {
    constexpr int BM = 64, BK = 16, NH = 64;
    __shared__ float As[BK][BM + 4];
    __shared__ float Bs[BK][NH + 4];
    __shared__ float red[16][NH];
    const int tid = threadIdx.x;
    const int m0 = blockIdx.x * BM;
    const int ty = tid >> 4, tx = tid & 15;
    const int ar = tid >> 2, ac = tid & 3;
    const int br = tid >> 4, bc = tid & 15;

    float acc[4][4] = {};
    for (int k0 = 0; k0 < DIM; k0 += BK) {
        float4 av = *(const float4*)&H[(size_t)(m0 + ar) * DIM + k0 + ac * 4];
        As[ac * 4 + 0][ar] = av.x;
        As[ac * 4 + 1][ar] = av.y;
        As[ac * 4 + 2][ar] = av.z;
        As[ac * 4 + 3][ar] = av.w;
        float4 bv = *(const float4*)&W1[(size_t)(k0 + br) * NH + bc * 4];
        Bs[br][bc * 4 + 0] = bv.x;
        Bs[br][bc * 4 + 1] = bv.y;
        Bs[br][bc * 4 + 2] = bv.z;
        Bs[br][bc * 4 + 3] = bv.w;
        __syncthreads();
#pragma unroll
        for (int k = 0; k < BK; ++k) {
            float a[4], b[4];
#pragma unroll
            for (int i = 0; i < 4; ++i) a[i] = As[k][ty * 4 + i];
#pragma unroll
            for (int j = 0; j < 4; ++j) b[j] = Bs[k][tx * 4 + j];
#pragma unroll
            for (int i = 0; i < 4; ++i)
#pragma unroll
                for (int j = 0; j < 4; ++j) acc[i][j] = fmaf(a[i], b[j], acc[i][j]);
        }
        __syncthreads();
    }
#pragma unroll
    for (int j = 0; j < 4; ++j) {
        const float bj = b1[tx * 4 + j];
        float sv = 0.f;
#pragma unroll
        for (int i = 0; i < 4; ++i) sv += fmaxf(acc[i][j] + bj, 0.f);
        red[ty][tx * 4 + j] = sv;
    }
    __syncthreads();
    if (tid < 64) {
        float t = 0.f;
        for (int r = 0; r < 16; ++r) t += red[r][tid];
        float h0 = t * W2[tid * 2 + 0];
        float h1 = t * W2[tid * 2 + 1];
#pragma unroll
        for (int off = 32; off > 0; off >>= 1) {
            h0 += __shfl_down(h0, off);
            h1 += __shfl_down(h1, off);
        }
        if (tid == 0) {
            partials[blockIdx.x * 2 + 0] = h0;
            partials[blockIdx.x * 2 + 1] = h1;
        }
    }
}

__global__ void finalize(const float* __restrict__ partials,
                         const float* __restrict__ b2, float* __restrict__ out) {
    const int l = threadIdx.x;
    float h0 = 0.f, h1 = 0.f;
    for (int i = l; i < 256; i += 64) {
        h0 += partials[2 * i + 0];
        h1 += partials[2 * i + 1];
    }
#pragma unroll
    for (int off = 32; off > 0; off >>= 1) {
        h0 += __shfl_down(h0, off);
        h1 += __shfl_down(h1, off);
    }
    if (l == 0) {
        h0 += (float)N_NODES * b2[0];
        h1 += (float)N_NODES * b2[1];
        const float m = fmaxf(h0, h1);
        const float e0 = __expf(h0 - m), e1 = __expf(h1 - m);
        out[(size_t)N_NODES * DIM + 0] = e0 / (e0 + e1);
        out[(size_t)N_NODES * DIM + 1] = e1 / (e0 + e1);
    }
}

extern "C" void kernel_launch(void* const* d_in, const int* in_sizes, int n_in,
                              void* d_out, int out_size, void* d_ws, size_t ws_size,
                              hipStream_t stream) {
    const float* X = (const float*)d_in[0];
    const int* in_idx = (const int*)d_in[1];
    const int* in_edge = (const int*)d_in[2];
    const float* in_mask = (const float*)d_in[3];
    const int* out_idx = (const int*)d_in[4];
    const int* out_edge = (const int*)d_in[5];
    const float* out_mask = (const float*)d_in[6];
    const float* Eemb = (const float*)d_in[7];
    const float* W_nb = (const float*)d_in[8];
    const float* b_nb = (const float*)d_in[9];
    const float* W_node = (const float*)d_in[10];
    // d_in[11] = b_node: softmax-invariant -> unused
    const float* attenW = (const float*)d_in[12];
    const float* W1 = (const float*)d_in[13];
    const float* b1 = (const float*)d_in[14];
    const float* W2 = (const float*)d_in[15];
    const float* b2 = (const float*)d_in[16];
    float* out = (float*)d_out;

    char* ws = (char*)d_ws;
    u16* Zh = (u16*)ws;                         // 16384*512*2 = 16 MiB (REP overlays)
    u16* XE = (u16*)(ws + 16777216);            // (16384+128)*256*2 = 8.06 MiB
    u16* Mhi = (u16*)(ws + 25231360);           // 256 KiB
    u16* Mlo = (u16*)(ws + 25493504);           // 256 KiB
    u16* WnbTh = (u16*)(ws + 25755648);         // 256 KiB
    float* partials = (float*)(ws + 26017792);  // 2 KiB

    pack_tables<<<2048, 256, 0, stream>>>(X, Eemb, W_nb, XE, WnbTh);
    build_M<<<512, 256, 0, stream>>>(W_node, attenW, Mhi, Mlo);
    gemm_z<<<dim3(128, 4), 256, 0, stream>>>(XE, Mhi, Mlo, Zh);
    gather_attn<<<N_NODES / NPB, 256, 0, stream>>>(XE, in_idx, in_edge, in_mask,
                                                   out_idx, out_edge, out_mask, Zh);
    gemm_h<<<dim3(128, 2), 256, 0, stream>>>(Zh, WnbTh, X, b_nb, out);
    mlp_reduce<<<N_NODES / 64, 256, 0, stream>>>(out, W1, b1, W2, partials);
    finalize<<<1, 64, 0, stream>>>(partials, b2, out);
}